// Round 7
// baseline (268.261 us; speedup 1.0000x reference)
//
#include <hip/hip_runtime.h>
#include <hip/hip_bf16.h>
#include <stdint.h>

#define D_IN   128
#define NPOLY  8256           // D*(D+1)/2
#define KDIM   8384           // D + NPOLY
#define B_ROWS 8192
#define N_COLS 512

// ---- workspace layout (bytes) ----
#define WBF_OFF   0
#define WBF_BYTES ((size_t)N_COLS * KDIM * 2)         // 8,585,216
#define FEA_OFF   WBF_BYTES
#define FEA_BYTES ((size_t)B_ROWS * KDIM * 2)         // 137,363,456
#define WS_NEED   (FEA_OFF + FEA_BYTES)               // ~146 MB

typedef __attribute__((ext_vector_type(8))) short    bf16x8_t;
typedef __attribute__((ext_vector_type(8))) float    f32x8_t;
typedef __attribute__((ext_vector_type(4))) float    f32x4_t;
typedef __attribute__((ext_vector_type(4))) uint32_t u32x4_t;

// one-instruction packed f32x2 -> bf16x2 (RNE on gfx950)
__device__ __forceinline__ uint32_t pk2(float lo, float hi) {
  uint32_t r;
  asm("v_cvt_pk_bf16_f32 %0, %1, %2" : "=v"(r) : "v"(lo), "v"(hi));
  return r;
}

__device__ __forceinline__ void async_load16(void* lds_dst, const void* g_src) {
  __builtin_amdgcn_global_load_lds(
      (const __attribute__((address_space(1))) void*)g_src,
      (__attribute__((address_space(3))) void*)lds_dst,
      16, 0, 0);
}

// ---------------- fused prep: feat_gen (2 rows/blk) | init_out | wconv -------
// (r6-proven; support time is dominated by fixed overhead + 137MB store BW,
//  so this is kept verbatim.)
#define NB_FEAT 4096   // 2 rows each
#define NB_INIT 4096   // out bias-init, float4
#define NB_WCNV 2096   // W f32->bf16, x8
__global__ __launch_bounds__(256) void fused_prep(
    const float* __restrict__ x, const float* __restrict__ w,
    const float* __restrict__ bias, float* __restrict__ out,
    uint16_t* __restrict__ wb, uint16_t* __restrict__ feats) {
  __shared__ float xs[2][D_IN];
  __shared__ __align__(16) uint16_t pr[2][KDIM];
  const int blk = blockIdx.x;
  const int tid = threadIdx.x;

  if (blk < NB_FEAT) {
    const int r0 = blk * 2;
    xs[tid >> 7][tid & 127] = x[(size_t)r0 * D_IN + tid];
    __syncthreads();
    if (tid < 32) {
      int row = tid >> 4, c8 = (tid & 15) * 8;
      u32x4_t o;
#pragma unroll
      for (int h = 0; h < 4; ++h)
        o[h] = pk2(xs[row][c8 + 2 * h], xs[row][c8 + 2 * h + 1]);
      *(u32x4_t*)&pr[row][c8] = o;
    }
    for (int it = 0; it < 5; ++it) {
      int g = tid + it * 256;
      if (g >= NPOLY / 8) break;
      int p0 = 8 * g;
      float t = 66049.0f - 8.0f * (float)p0;
      int i = (int)((257.0f - sqrtf(t)) * 0.5f);
      if (i < 0) i = 0; if (i > 127) i = 127;
      while (i > 0 && (i * (257 - i)) / 2 > p0) --i;
      while (i < 127 && ((i + 1) * (257 - (i + 1))) / 2 <= p0) ++i;
      int j = i + (p0 - (i * (257 - i)) / 2);
      float xi0 = xs[0][i], xi1 = xs[1][i];
      float q0[8], q1[8];
#pragma unroll
      for (int e = 0; e < 8; ++e) {
        q0[e] = xi0 * xs[0][j];
        q1[e] = xi1 * xs[1][j];
        if (e < 7) {
          if (j == 127) { ++i; j = i; xi0 = xs[0][i]; xi1 = xs[1][i]; }
          else ++j;
        }
      }
      u32x4_t o0, o1;
#pragma unroll
      for (int h = 0; h < 4; ++h) {
        o0[h] = pk2(q0[2 * h], q0[2 * h + 1]);
        o1[h] = pk2(q1[2 * h], q1[2 * h + 1]);
      }
      *(u32x4_t*)&pr[0][D_IN + p0] = o0;
      *(u32x4_t*)&pr[1][D_IN + p0] = o1;
    }
    __syncthreads();
    uint16_t* d0 = feats + (size_t)r0 * KDIM;
    for (int q = tid; q < 2 * (KDIM / 8); q += 256) {
      int row = (q >= KDIM / 8);
      int g = q - (row ? KDIM / 8 : 0);
      *(bf16x8_t*)(d0 + (size_t)row * KDIM + g * 8) =
          *(const bf16x8_t*)&pr[row][g * 8];
    }
  } else if (blk < NB_FEAT + NB_INIT) {
    int idx = (blk - NB_FEAT) * 256 + tid;
    f32x4_t bv = *(const f32x4_t*)(bias + ((idx * 4) & (N_COLS - 1)));
    *(f32x4_t*)(out + (size_t)idx * 4) = bv;
  } else {
    int g = (blk - NB_FEAT - NB_INIT) * 256 + tid;
    f32x8_t v = *(const f32x8_t*)(w + (size_t)g * 8);
    u32x4_t o;
#pragma unroll
    for (int h = 0; h < 4; ++h) o[h] = pk2(v[2 * h], v[2 * h + 1]);
    *(u32x4_t*)(wb + (size_t)g * 8) = o;
  }
}

// ---------------- bf16 MFMA GEMM: out += feats @ W^T ----------------
// BM=BN=128, BK=64, 4 waves (2x2), split-K=2. New pipeline:
//  - A staged global_load_lds -> DOUBLE-buffered sA, pre-swizzled source.
//  - W fragments loaded DIRECT to registers, 2-phase (bX/bY) one step ahead.
//  - raw s_barrier + counted s_waitcnt vmcnt(12): loads for t+1 stay in
//    flight across both barriers (never drained to 0 in-loop).
//  - XCD-bijective block swizzle: one (by,bz) W-panel (2.1MB) per XCD -> L2.
#define BMT 128
#define BNT 128
#define BKT 64
#define KSTEPS 131   // 8384/64
#define KCUT 66      // split: [0,66) and [66,131)

__global__ __launch_bounds__(256, 2) void gemm_poly(
    const uint16_t* __restrict__ A,   // feats bf16 [B_ROWS][KDIM]
    const uint16_t* __restrict__ W,   // bf16 [N_COLS][KDIM]
    float* __restrict__ out) {
  __shared__ __align__(16) uint16_t sA[2 * BMT * BKT];   // 2 x 16 KB

  const int tid  = threadIdx.x;
  const int lane = tid & 63;
  const int wv   = tid >> 6;
  const int wr   = wv >> 1;     // wave row (0..1)
  const int wc   = wv & 1;      // wave col (0..1)
  const int hi   = lane >> 4;   // 0..3
  const int lr   = lane & 15;

  // XCD-bijective decode: 512 blocks, 64/XCD; each XCD gets one (by,bz)
  // panel with bx sweeping -> W-panel (2.1 MB) L2-resident per XCD.
  const int bid = blockIdx.x;
  const int lin = (bid & 7) * 64 + (bid >> 3);
  const int bz  = lin >> 8;
  const int rem = lin & 255;
  const int by  = rem >> 6;
  const int bx  = rem & 63;

  const int b0  = bx * BMT;
  const int n0  = by * BNT;
  const int kt0 = (bz == 0) ? 0 : KCUT;
  const int kt1 = (bz == 0) ? KCUT : KSTEPS;

  // A staging geometry (r1-proven): linear LDS L = q*4096 + tid*16
  int rowq[4], cbxq[4];
#pragma unroll
  for (int q = 0; q < 4; ++q) {
    int L = q * 4096 + tid * 16;
    int row = L >> 7;
    int cb  = L & 127;
    rowq[q] = row;
    cbxq[q] = cb ^ ((row & 7) << 4);   // inverse-swizzled source chunk
  }

  // A-fragment LDS byte offsets (same XOR on read)
  int offA[4][2];
#pragma unroll
  for (int f = 0; f < 4; ++f) {
    int rowA = wr * 64 + f * 16 + lr;
#pragma unroll
    for (int kh = 0; kh < 2; ++kh) {
      int kb = kh * 64 + hi * 16;
      offA[f][kh] = rowA * 128 + (kb ^ ((rowA & 7) << 4));
    }
  }

  // W per-lane base pointers (row-major K-contiguous == B-fragment layout)
  const char* Wb = (const char*)W;
  const char* wbase[4];
#pragma unroll
  for (int nf = 0; nf < 4; ++nf) {
    int rowW = n0 + wc * 64 + nf * 16 + lr;
    wbase[nf] = Wb + (size_t)rowW * (KDIM * 2) + hi * 16;
  }

  f32x4_t acc[4][4];
#pragma unroll
  for (int mf = 0; mf < 4; ++mf)
#pragma unroll
    for (int nf = 0; nf < 4; ++nf) {
      f32x4_t z = {0.f, 0.f, 0.f, 0.f};
      acc[mf][nf] = z;
    }

  const char* Ab = (const char*)A;

#define STAGE_A(kt, P)                                                         \
  {                                                                            \
    _Pragma("unroll")                                                          \
    for (int q = 0; q < 4; ++q) {                                              \
      const char* srcA =                                                       \
          Ab + ((size_t)(b0 + rowq[q]) * KDIM + (kt) * BKT) * 2 + cbxq[q];     \
      async_load16((char*)sA + (P) * 16384 + q * 4096 + tid * 16, srcA);       \
    }                                                                          \
  }

#define LOADW(DST, kt)                                                         \
  {                                                                            \
    _Pragma("unroll")                                                          \
    for (int nf = 0; nf < 4; ++nf) {                                           \
      DST[nf][0] = *(const bf16x8_t*)(wbase[nf] + (kt) * 128);                 \
      DST[nf][1] = *(const bf16x8_t*)(wbase[nf] + (kt) * 128 + 64);            \
    }                                                                          \
  }

// One K-step: issue next-step loads, counted wait for current, barrier,
// fragments + MFMA, barrier. P is the sA buffer parity (literal 0/1).
#define ITER(T, BCUR, BNXT, P)                                                 \
  {                                                                            \
    const int t_ = (T);                                                        \
    if (t_ + 1 < kt1) {                                                        \
      LOADW(BNXT, t_ + 1);                                                     \
      STAGE_A(t_ + 1, (P) ^ 1);                                                \
      asm volatile("s_waitcnt vmcnt(12)" ::: "memory");                        \
    } else {                                                                   \
      asm volatile("s_waitcnt vmcnt(0)" ::: "memory");                         \
    }                                                                          \
    __builtin_amdgcn_s_barrier();                                              \
    __builtin_amdgcn_sched_barrier(0);                                         \
    bf16x8_t a_[4][2];                                                         \
    _Pragma("unroll")                                                          \
    for (int mf = 0; mf < 4; ++mf) {                                           \
      a_[mf][0] = *(const bf16x8_t*)((const char*)sA + (P) * 16384 +           \
                                     offA[mf][0]);                             \
      a_[mf][1] = *(const bf16x8_t*)((const char*)sA + (P) * 16384 +           \
                                     offA[mf][1]);                             \
    }                                                                          \
    __builtin_amdgcn_s_setprio(1);                                             \
    _Pragma("unroll")                                                          \
    for (int mf = 0; mf < 4; ++mf)                                             \
      _Pragma("unroll")                                                        \
      for (int nf = 0; nf < 4; ++nf) {                                         \
        acc[mf][nf] = __builtin_amdgcn_mfma_f32_16x16x32_bf16(                 \
            a_[mf][0], BCUR[nf][0], acc[mf][nf], 0, 0, 0);                     \
        acc[mf][nf] = __builtin_amdgcn_mfma_f32_16x16x32_bf16(                 \
            a_[mf][1], BCUR[nf][1], acc[mf][nf], 0, 0, 0);                     \
      }                                                                        \
    __builtin_amdgcn_s_setprio(0);                                             \
    __builtin_amdgcn_s_barrier();                                              \
    __builtin_amdgcn_sched_barrier(0);                                         \
  }

  bf16x8_t bX[4][2], bY[4][2];
  STAGE_A(kt0, 0);
  LOADW(bX, kt0);

  const int iters = kt1 - kt0;
  for (int it = 0; it < iters; it += 2) {
    ITER(kt0 + it, bX, bY, 0);
    if (it + 1 < iters) ITER(kt0 + it + 1, bY, bX, 1);
  }

  // epilogue: C/D layout col=lane&15, row=(lane>>4)*4+reg
#pragma unroll
  for (int mf = 0; mf < 4; ++mf) {
    int row = b0 + wr * 64 + mf * 16 + hi * 4;
#pragma unroll
    for (int nf = 0; nf < 4; ++nf) {
      int col = n0 + wc * 64 + nf * 16 + lr;
#pragma unroll
      for (int r = 0; r < 4; ++r) {
        atomicAdd(&out[(size_t)(row + r) * N_COLS + col], acc[mf][nf][r]);
      }
    }
  }
#undef ITER
#undef LOADW
#undef STAGE_A
}

// ---------------- naive fallback (only if ws too small) ----------------
__global__ void naive_poly(const float* __restrict__ x, const float* __restrict__ w,
                           const float* __restrict__ bias, float* __restrict__ out) {
  size_t o = (size_t)blockIdx.x * 256 + threadIdx.x;
  if (o >= (size_t)B_ROWS * N_COLS) return;
  int n = (int)(o >> 13);
  int b = (int)(o & (B_ROWS - 1));
  const float* xr = x + (size_t)b * D_IN;
  const float* wr = w + (size_t)n * KDIM;
  float acc = bias[n];
  for (int k = 0; k < D_IN; ++k) acc += wr[k] * xr[k];
  int p = D_IN;
  for (int i = 0; i < D_IN; ++i) {
    float xi = xr[i];
    for (int j = i; j < D_IN; ++j) acc += wr[p++] * xi * xr[j];
  }
  out[(size_t)b * N_COLS + n] = acc;
}

extern "C" void kernel_launch(void* const* d_in, const int* in_sizes, int n_in,
                              void* d_out, int out_size, void* d_ws, size_t ws_size,
                              hipStream_t stream) {
  const float* x    = (const float*)d_in[0];
  const float* w    = (const float*)d_in[1];
  const float* bias = (const float*)d_in[2];
  float* out = (float*)d_out;

  if (ws_size < WS_NEED) {   // safety net: correct but slow
    naive_poly<<<(B_ROWS * N_COLS) / 256, 256, 0, stream>>>(x, w, bias, out);
    return;
  }

  char* ws = (char*)d_ws;
  uint16_t* wb  = (uint16_t*)(ws + WBF_OFF);
  uint16_t* fe  = (uint16_t*)(ws + FEA_OFF);

  fused_prep<<<NB_FEAT + NB_INIT + NB_WCNV, 256, 0, stream>>>(x, w, bias, out, wb, fe);
  gemm_poly<<<512, 256, 0, stream>>>(fe, wb, out);
}

// Round 8
// 200.193 us; speedup vs baseline: 1.3400x; 1.3400x over previous
//
#include <hip/hip_runtime.h>
#include <hip/hip_bf16.h>
#include <stdint.h>

#define D_IN   128
#define NPOLY  8256           // D*(D+1)/2
#define KDIM   8384           // D + NPOLY
#define B_ROWS 8192
#define N_COLS 512

// ---- workspace layout (bytes) ----
#define WBF_OFF   0
#define WBF_BYTES ((size_t)N_COLS * KDIM * 2)         // 8,585,216
#define FEA_OFF   WBF_BYTES
#define FEA_BYTES ((size_t)B_ROWS * KDIM * 2)         // 137,363,456
#define WS_NEED   (FEA_OFF + FEA_BYTES)               // ~146 MB

typedef __attribute__((ext_vector_type(8))) short    bf16x8_t;
typedef __attribute__((ext_vector_type(8))) float    f32x8_t;
typedef __attribute__((ext_vector_type(4))) float    f32x4_t;
typedef __attribute__((ext_vector_type(4))) uint32_t u32x4_t;

// one-instruction packed f32x2 -> bf16x2 (RNE on gfx950)
__device__ __forceinline__ uint32_t pk2(float lo, float hi) {
  uint32_t r;
  asm("v_cvt_pk_bf16_f32 %0, %1, %2" : "=v"(r) : "v"(lo), "v"(hi));
  return r;
}

__device__ __forceinline__ void async_load16(void* lds_dst, const void* g_src) {
  __builtin_amdgcn_global_load_lds(
      (const __attribute__((address_space(1))) void*)g_src,
      (__attribute__((address_space(3))) void*)lds_dst,
      16, 0, 0);
}

// ---------------- fused prep: feat_gen (2 rows/blk) | init_out | wconv -------
// (r6-proven, kept verbatim)
#define NB_FEAT 4096   // 2 rows each
#define NB_INIT 4096   // out bias-init, float4
#define NB_WCNV 2096   // W f32->bf16, x8
__global__ __launch_bounds__(256) void fused_prep(
    const float* __restrict__ x, const float* __restrict__ w,
    const float* __restrict__ bias, float* __restrict__ out,
    uint16_t* __restrict__ wb, uint16_t* __restrict__ feats) {
  __shared__ float xs[2][D_IN];
  __shared__ __align__(16) uint16_t pr[2][KDIM];
  const int blk = blockIdx.x;
  const int tid = threadIdx.x;

  if (blk < NB_FEAT) {
    const int r0 = blk * 2;
    xs[tid >> 7][tid & 127] = x[(size_t)r0 * D_IN + tid];
    __syncthreads();
    if (tid < 32) {
      int row = tid >> 4, c8 = (tid & 15) * 8;
      u32x4_t o;
#pragma unroll
      for (int h = 0; h < 4; ++h)
        o[h] = pk2(xs[row][c8 + 2 * h], xs[row][c8 + 2 * h + 1]);
      *(u32x4_t*)&pr[row][c8] = o;
    }
    for (int it = 0; it < 5; ++it) {
      int g = tid + it * 256;
      if (g >= NPOLY / 8) break;
      int p0 = 8 * g;
      float t = 66049.0f - 8.0f * (float)p0;
      int i = (int)((257.0f - sqrtf(t)) * 0.5f);
      if (i < 0) i = 0; if (i > 127) i = 127;
      while (i > 0 && (i * (257 - i)) / 2 > p0) --i;
      while (i < 127 && ((i + 1) * (257 - (i + 1))) / 2 <= p0) ++i;
      int j = i + (p0 - (i * (257 - i)) / 2);
      float xi0 = xs[0][i], xi1 = xs[1][i];
      float q0[8], q1[8];
#pragma unroll
      for (int e = 0; e < 8; ++e) {
        q0[e] = xi0 * xs[0][j];
        q1[e] = xi1 * xs[1][j];
        if (e < 7) {
          if (j == 127) { ++i; j = i; xi0 = xs[0][i]; xi1 = xs[1][i]; }
          else ++j;
        }
      }
      u32x4_t o0, o1;
#pragma unroll
      for (int h = 0; h < 4; ++h) {
        o0[h] = pk2(q0[2 * h], q0[2 * h + 1]);
        o1[h] = pk2(q1[2 * h], q1[2 * h + 1]);
      }
      *(u32x4_t*)&pr[0][D_IN + p0] = o0;
      *(u32x4_t*)&pr[1][D_IN + p0] = o1;
    }
    __syncthreads();
    uint16_t* d0 = feats + (size_t)r0 * KDIM;
    for (int q = tid; q < 2 * (KDIM / 8); q += 256) {
      int row = (q >= KDIM / 8);
      int g = q - (row ? KDIM / 8 : 0);
      *(bf16x8_t*)(d0 + (size_t)row * KDIM + g * 8) =
          *(const bf16x8_t*)&pr[row][g * 8];
    }
  } else if (blk < NB_FEAT + NB_INIT) {
    int idx = (blk - NB_FEAT) * 256 + tid;
    f32x4_t bv = *(const f32x4_t*)(bias + ((idx * 4) & (N_COLS - 1)));
    *(f32x4_t*)(out + (size_t)idx * 4) = bv;
  } else {
    int g = (blk - NB_FEAT - NB_INIT) * 256 + tid;
    f32x8_t v = *(const f32x8_t*)(w + (size_t)g * 8);
    u32x4_t o;
#pragma unroll
    for (int h = 0; h < 4; ++h) o[h] = pk2(v[2 * h], v[2 * h + 1]);
    *(u32x4_t*)(wb + (size_t)g * 8) = o;
  }
}

// ---------------- bf16 MFMA GEMM: out += feats @ W^T ----------------
// r1 structure + T3-minimum pipeline: double-buffered sA/sW, ONE barrier per
// K-step, STAGE(t+1) issued BEFORE ds_read+MFMA(t) so the vmcnt(0) inside
// __syncthreads lands after ~600cyc of compute (near-free). Both operands
// staged via global_load_lds(16B) with pre-swizzled source (conflict-free
// ds_read_b128). Grid = natural dim3(64,4,2) (r1-proven).
#define BMT 128
#define BNT 128
#define BKT 64
#define KSTEPS 131   // 8384/64
#define KCUT 66      // split: [0,66) and [66,131)

__global__ __launch_bounds__(256, 2) void gemm_poly(
    const uint16_t* __restrict__ A,   // feats bf16 [B_ROWS][KDIM]
    const uint16_t* __restrict__ W,   // bf16 [N_COLS][KDIM]
    float* __restrict__ out) {
  __shared__ __align__(16) uint16_t sA[2][BMT * BKT];   // 2 x 16 KB
  __shared__ __align__(16) uint16_t sW[2][BNT * BKT];   // 2 x 16 KB

  const int tid  = threadIdx.x;
  const int lane = tid & 63;
  const int wv   = tid >> 6;
  const int wr   = wv >> 1;     // wave row (0..1)
  const int wc   = wv & 1;      // wave col (0..1)
  const int hi   = lane >> 4;   // 0..3
  const int lr   = lane & 15;

  const int b0 = blockIdx.x * BMT;
  const int n0 = blockIdx.y * BNT;
  const int kt0 = (blockIdx.z == 0) ? 0 : KCUT;
  const int kt1 = (blockIdx.z == 0) ? KCUT : KSTEPS;

  // staging geometry: linear LDS offset L = q*4096 + tid*16 -> (row, cb)
  int rowq[4], cbxq[4];
#pragma unroll
  for (int q = 0; q < 4; ++q) {
    int L = q * 4096 + tid * 16;
    int row = L >> 7;          // 128 B per row
    int cb  = L & 127;
    rowq[q] = row;
    cbxq[q] = cb ^ ((row & 7) << 4);   // inverse-swizzled source chunk
  }

  // fragment LDS byte offsets within one buffer (same XOR on read)
  int offA[4][2], offW[4][2];
#pragma unroll
  for (int f = 0; f < 4; ++f) {
    int rowA = wr * 64 + f * 16 + lr;
    int rowW = wc * 64 + f * 16 + lr;
#pragma unroll
    for (int kh = 0; kh < 2; ++kh) {
      int kb = kh * 64 + hi * 16;
      offA[f][kh] = rowA * 128 + (kb ^ ((rowA & 7) << 4));
      offW[f][kh] = rowW * 128 + (kb ^ ((rowW & 7) << 4));
    }
  }

  f32x4_t acc[4][4];
#pragma unroll
  for (int mf = 0; mf < 4; ++mf)
#pragma unroll
    for (int nf = 0; nf < 4; ++nf) {
      f32x4_t z = {0.f, 0.f, 0.f, 0.f};
      acc[mf][nf] = z;
    }

  const char* Ab = (const char*)A;
  const char* Wb = (const char*)W;

#define STAGE(buf, kt)                                                         \
  {                                                                            \
    _Pragma("unroll")                                                          \
    for (int q = 0; q < 4; ++q) {                                              \
      const char* srcA =                                                       \
          Ab + ((size_t)(b0 + rowq[q]) * KDIM + (kt) * BKT) * 2 + cbxq[q];     \
      async_load16((char*)sA[buf] + q * 4096 + tid * 16, srcA);                \
    }                                                                          \
    _Pragma("unroll")                                                          \
    for (int q = 0; q < 4; ++q) {                                              \
      const char* srcW =                                                       \
          Wb + ((size_t)(n0 + rowq[q]) * KDIM + (kt) * BKT) * 2 + cbxq[q];     \
      async_load16((char*)sW[buf] + q * 4096 + tid * 16, srcW);                \
    }                                                                          \
  }

  STAGE(0, kt0);
  __syncthreads();                 // prologue drain (once)
  int cur = 0;
  for (int kt = kt0; kt < kt1; ++kt) {
    if (kt + 1 < kt1) STAGE(cur ^ 1, kt + 1);   // issue-early prefetch
    __builtin_amdgcn_sched_barrier(0);          // keep issue before compute
    bf16x8_t a[4][2], b[4][2];
#pragma unroll
    for (int mf = 0; mf < 4; ++mf)
#pragma unroll
      for (int kh = 0; kh < 2; ++kh)
        a[mf][kh] = *(const bf16x8_t*)((const char*)sA[cur] + offA[mf][kh]);
#pragma unroll
    for (int nf = 0; nf < 4; ++nf)
#pragma unroll
      for (int kh = 0; kh < 2; ++kh)
        b[nf][kh] = *(const bf16x8_t*)((const char*)sW[cur] + offW[nf][kh]);
    __builtin_amdgcn_s_setprio(1);
#pragma unroll
    for (int mf = 0; mf < 4; ++mf)
#pragma unroll
      for (int nf = 0; nf < 4; ++nf) {
        acc[mf][nf] = __builtin_amdgcn_mfma_f32_16x16x32_bf16(
            a[mf][0], b[nf][0], acc[mf][nf], 0, 0, 0);
        acc[mf][nf] = __builtin_amdgcn_mfma_f32_16x16x32_bf16(
            a[mf][1], b[nf][1], acc[mf][nf], 0, 0, 0);
      }
    __builtin_amdgcn_s_setprio(0);
    __syncthreads();   // ONE barrier: t+1 writes visible, cur-buf reads retired
    cur ^= 1;
  }

  // epilogue: C/D layout col=lane&15, row=(lane>>4)*4+reg
#pragma unroll
  for (int mf = 0; mf < 4; ++mf) {
    int row = b0 + wr * 64 + mf * 16 + hi * 4;
#pragma unroll
    for (int nf = 0; nf < 4; ++nf) {
      int col = n0 + wc * 64 + nf * 16 + lr;
#pragma unroll
      for (int r = 0; r < 4; ++r) {
        atomicAdd(&out[(size_t)(row + r) * N_COLS + col], acc[mf][nf][r]);
      }
    }
  }
#undef STAGE
}

// ---------------- naive fallback (only if ws too small) ----------------
__global__ void naive_poly(const float* __restrict__ x, const float* __restrict__ w,
                           const float* __restrict__ bias, float* __restrict__ out) {
  size_t o = (size_t)blockIdx.x * 256 + threadIdx.x;
  if (o >= (size_t)B_ROWS * N_COLS) return;
  int n = (int)(o >> 13);
  int b = (int)(o & (B_ROWS - 1));
  const float* xr = x + (size_t)b * D_IN;
  const float* wr = w + (size_t)n * KDIM;
  float acc = bias[n];
  for (int k = 0; k < D_IN; ++k) acc += wr[k] * xr[k];
  int p = D_IN;
  for (int i = 0; i < D_IN; ++i) {
    float xi = xr[i];
    for (int j = i; j < D_IN; ++j) acc += wr[p++] * xi * xr[j];
  }
  out[(size_t)b * N_COLS + n] = acc;
}

extern "C" void kernel_launch(void* const* d_in, const int* in_sizes, int n_in,
                              void* d_out, int out_size, void* d_ws, size_t ws_size,
                              hipStream_t stream) {
  const float* x    = (const float*)d_in[0];
  const float* w    = (const float*)d_in[1];
  const float* bias = (const float*)d_in[2];
  float* out = (float*)d_out;

  if (ws_size < WS_NEED) {   // safety net: correct but slow
    naive_poly<<<(B_ROWS * N_COLS) / 256, 256, 0, stream>>>(x, w, bias, out);
    return;
  }

  char* ws = (char*)d_ws;
  uint16_t* wb  = (uint16_t*)(ws + WBF_OFF);
  uint16_t* fe  = (uint16_t*)(ws + FEA_OFF);

  fused_prep<<<NB_FEAT + NB_INIT + NB_WCNV, 256, 0, stream>>>(x, w, bias, out, wb, fe);
  gemm_poly<<<dim3(B_ROWS / BMT, N_COLS / BNT, 2), 256, 0, stream>>>(fe, wb, out);
}